// Round 7
// baseline (214.932 us; speedup 1.0000x reference)
//
#include <hip/hip_runtime.h>
#include <math.h>

// ---------------------------------------------------------------------------
// ClustGeoNodeEncoder via two-level bucket decomposition.
//
// Measured walls: global atomics ~16-23 G ops/s (r2-r4); LDS-atomic moments at
// low block count serialize (r5); redundant per-wave f64 eigen is VALU-heavy
// (r6). Design:
//   p1_bucket   : bucket = cid>>8 (196 buckets). Per 4096-voxel round: LDS
//                 ds_add_rtn local ranks + 256 returning global atomics
//                 allocate bucket space; scatter (x,y,z,cid)->bbuf and the
//                 low cid byte -> lcb (so p2's sort passes read 1B/pt).
//   p2_features : 8 blocks per bucket (32 clusters each, 512 thr, grid 1568).
//                 A: hist+scan+counting-sort indices (LDS, from lcb bytes)
//                 B: wave gathers its 4 clusters' points into REGISTERS,
//                    shuffle-reduces 9 moments -> LDS
//                 C: lane-per-cluster f64 eigen (32 lanes of wave 0) ->
//                    center/B/size written, cen/v0/dirwt -> LDS
//                 D: sc from the registers held since B -> final v0 write
// Fallback (small ws): round-2 packed u64 fixed-point pipeline.
// ---------------------------------------------------------------------------

#define CAP 24576          // per-bucket capacity (expected 20480 @ bench; +20%)
#define SPLIT 8
#define CLB 32             // clusters per p2 block (256/SPLIT)
#define IDXCAP 4096        // per-split-block index capacity (expected ~2560)

// ========================= shared: 3x3 symmetric eigen =====================
__device__ inline void eig3_sym(double a00, double a01, double a02,
                                double a11, double a12, double a22,
                                double& w0, double& w1, double& w2,
                                double v[3]) {
    double p1 = a01 * a01 + a02 * a02 + a12 * a12;
    double q  = (a00 + a11 + a22) / 3.0;
    double d0 = a00 - q, d1 = a11 - q, d2 = a22 - q;
    double p2 = d0 * d0 + d1 * d1 + d2 * d2 + 2.0 * p1;
    double p  = sqrt(p2 / 6.0);
    if (p < 1e-300) {
        w0 = w1 = w2 = q;
        v[0] = 0.0; v[1] = 0.0; v[2] = 1.0;
        return;
    }
    double ip = 1.0 / p;
    double b00 = d0 * ip, b11 = d1 * ip, b22 = d2 * ip;
    double b01 = a01 * ip, b02 = a02 * ip, b12 = a12 * ip;
    double detB = b00 * (b11 * b22 - b12 * b12)
                - b01 * (b01 * b22 - b12 * b02)
                + b02 * (b01 * b12 - b11 * b02);
    double r = detB * 0.5;
    r = fmin(1.0, fmax(-1.0, r));
    double phi = acos(r) / 3.0;
    w2 = q + 2.0 * p * cos(phi);
    w0 = q + 2.0 * p * cos(phi + 2.0943951023931953);  // +2*pi/3
    w1 = 3.0 * q - w2 - w0;

    double r0x = a00 - w2, r0y = a01,       r0z = a02;
    double r1x = a01,      r1y = a11 - w2,  r1z = a12;
    double r2x = a02,      r2y = a12,       r2z = a22 - w2;

    double c0x = r0y * r1z - r0z * r1y;
    double c0y = r0z * r1x - r0x * r1z;
    double c0z = r0x * r1y - r0y * r1x;
    double n0  = c0x * c0x + c0y * c0y + c0z * c0z;

    double c1x = r0y * r2z - r0z * r2y;
    double c1y = r0z * r2x - r0x * r2z;
    double c1z = r0x * r2y - r0y * r2x;
    double n1  = c1x * c1x + c1y * c1y + c1z * c1z;

    double c2x = r1y * r2z - r1z * r2y;
    double c2y = r1z * r2x - r1x * r2z;
    double c2z = r1x * r2y - r1y * r2x;
    double n2  = c2x * c2x + c2y * c2y + c2z * c2z;

    double vx, vy, vz, nn;
    if (n0 >= n1 && n0 >= n2) { vx = c0x; vy = c0y; vz = c0z; nn = n0; }
    else if (n1 >= n2)        { vx = c1x; vy = c1y; vz = c1z; nn = n1; }
    else                      { vx = c2x; vy = c2y; vz = c2z; nn = n2; }
    if (nn < 1e-300) {
        v[0] = 0.0; v[1] = 0.0; v[2] = 1.0;
        return;
    }
    double inv = rsqrt(nn);
    v[0] = vx * inv; v[1] = vy * inv; v[2] = vz * inv;
}

// ============================ primary path =================================
#define P1_BLOCK 1024
#define P1_ITEMS 4     // voxels per thread per round -> 4096 per block-round

__global__ void p1_bucket(const float* __restrict__ data,
                          const int* __restrict__ cid,
                          unsigned int* __restrict__ gcnt,     // [256]
                          float4* __restrict__ bbuf,           // [nb*CAP]
                          unsigned char* __restrict__ lcb,     // [nb*CAP]
                          int n_vox) {
    __shared__ unsigned int hist[256];
    __shared__ unsigned int base[256];
    const int tid = threadIdx.x;
    const int per_round = P1_BLOCK * P1_ITEMS;
    const int total_rounds = (n_vox + per_round - 1) / per_round;

    for (int r = blockIdx.x; r < total_rounds; r += gridDim.x) {
        const int start = r * per_round;
        if (tid < 256) hist[tid] = 0;
        __syncthreads();

        int   bk[P1_ITEMS];
        int   cd[P1_ITEMS];
        float px[P1_ITEMS], py[P1_ITEMS], pz[P1_ITEMS];
        unsigned int rk[P1_ITEMS];
#pragma unroll
        for (int k = 0; k < P1_ITEMS; ++k) {
            int i = start + tid + k * P1_BLOCK;   // coalesced lane pattern
            if (i < n_vox) {
                int c = cid[i];
                cd[k] = c;
                bk[k] = c >> 8;
                const float* row = data + (size_t)i * 6;
                px[k] = row[1]; py[k] = row[2]; pz[k] = row[3];
                rk[k] = atomicAdd(&hist[bk[k]], 1u);   // local rank
            } else {
                bk[k] = -1;
            }
        }
        __syncthreads();
        if (tid < 256) {
            unsigned int h = hist[tid];
            base[tid] = h ? atomicAdd(&gcnt[tid], h) : 0u;
        }
        __syncthreads();
#pragma unroll
        for (int k = 0; k < P1_ITEMS; ++k) {
            if (bk[k] >= 0) {
                unsigned int pos = base[bk[k]] + rk[k];
                if (pos < (unsigned int)CAP) {
                    bbuf[(size_t)bk[k] * CAP + pos] =
                        make_float4(px[k], py[k], pz[k], __int_as_float(cd[k]));
                    lcb[(size_t)bk[k] * CAP + pos] = (unsigned char)(cd[k] & 255);
                }
            }
        }
        __syncthreads();
    }
}

__global__ __launch_bounds__(512) void p2_features(
        const unsigned int* __restrict__ gcnt,
        const float4* __restrict__ bbuf,
        const unsigned char* __restrict__ lcb,
        float* __restrict__ out, int C) {
    __shared__ unsigned int hist[CLB];
    __shared__ unsigned int basex[CLB];
    __shared__ unsigned int hist2[CLB];
    __shared__ unsigned short idx16[IDXCAP];
    __shared__ float mom[9][CLB];
    __shared__ float cenl[3][CLB], vvl[3][CLB], dwl[CLB];

    const int b    = blockIdx.x / SPLIT;
    const int part = blockIdx.x % SPLIT;
    const int lo   = part * CLB;               // local cluster range [lo,lo+32)
    const int tid  = threadIdx.x;
    const int bcnt = min((int)gcnt[b], CAP);
    const float4* src = bbuf + (size_t)b * CAP;
    const unsigned char* lc8 = lcb + (size_t)b * CAP;

    if (tid < CLB) { hist[tid] = 0; hist2[tid] = 0; }
    __syncthreads();

    // ---- A1: histogram of this block's 32 clusters ----
    for (int i = tid; i < bcnt; i += 512) {
        int lc = (int)lc8[i] - lo;
        if ((unsigned)lc < CLB) atomicAdd(&hist[lc], 1u);
    }
    __syncthreads();

    // ---- scan (exclusive) over 32 entries, wave 0 ----
    if (tid < CLB) {
        unsigned int h = hist[tid];
        unsigned int inc = h;
        for (int off = 1; off < CLB; off <<= 1) {
            unsigned int t = __shfl_up(inc, off);
            if (tid >= off) inc += t;
        }
        basex[tid] = inc - h;
    }
    __syncthreads();

    // ---- A2: counting-sort indices ----
    for (int i = tid; i < bcnt; i += 512) {
        int lc = (int)lc8[i] - lo;
        if ((unsigned)lc < CLB) {
            unsigned int rk = atomicAdd(&hist2[lc], 1u);
            unsigned int pos = basex[lc] + rk;
            if (pos < IDXCAP) idx16[pos] = (unsigned short)i;
        }
    }
    __syncthreads();

    // ---- B: wave-per-cluster moments, points held in registers ----
    const int w    = tid >> 6;     // 0..7
    const int lane = tid & 63;

    float4 qa[4], qb[4];
    int    nn[4];
    unsigned int nbs[4];

#pragma unroll
    for (int jj = 0; jj < 4; ++jj) {
        const int lc = (w << 2) | jj;
        const int n  = (int)hist[lc];
        const unsigned int nb = basex[lc];
        nn[jj] = n; nbs[jj] = nb;
        float4 z = make_float4(0.f, 0.f, 0.f, 0.f);
        float4 q0 = z, q1 = z;
        unsigned int p0 = nb + (unsigned)lane, p1 = p0 + 64u;
        if (lane < n && p0 < IDXCAP) q0 = src[idx16[p0]];
        if (lane + 64 < n && p1 < IDXCAP) q1 = src[idx16[p1]];
        qa[jj] = q0; qb[jj] = q1;

        float s0 = q0.x + q1.x;
        float s1 = q0.y + q1.y;
        float s2 = q0.z + q1.z;
        float s3 = q0.x * q0.x + q1.x * q1.x;
        float s4 = q0.x * q0.y + q1.x * q1.y;
        float s5 = q0.x * q0.z + q1.x * q1.z;
        float s6 = q0.y * q0.y + q1.y * q1.y;
        float s7 = q0.y * q0.z + q1.y * q1.z;
        float s8 = q0.z * q0.z + q1.z * q1.z;
        for (int j = lane + 128; j < n; j += 64) {       // rare n>128 tail
            unsigned int pp = nb + (unsigned)j;
            if (pp < IDXCAP) {
                float4 p = src[idx16[pp]];
                s0 += p.x;       s1 += p.y;       s2 += p.z;
                s3 += p.x * p.x; s4 += p.x * p.y; s5 += p.x * p.z;
                s6 += p.y * p.y; s7 += p.y * p.z; s8 += p.z * p.z;
            }
        }
#pragma unroll
        for (int d = 32; d > 0; d >>= 1) {
            s0 += __shfl_xor(s0, d); s1 += __shfl_xor(s1, d); s2 += __shfl_xor(s2, d);
            s3 += __shfl_xor(s3, d); s4 += __shfl_xor(s4, d); s5 += __shfl_xor(s5, d);
            s6 += __shfl_xor(s6, d); s7 += __shfl_xor(s7, d); s8 += __shfl_xor(s8, d);
        }
        if (lane == 0) {
            mom[0][lc] = s0; mom[1][lc] = s1; mom[2][lc] = s2;
            mom[3][lc] = s3; mom[4][lc] = s4; mom[5][lc] = s5;
            mom[6][lc] = s6; mom[7][lc] = s7; mom[8][lc] = s8;
        }
    }
    __syncthreads();

    // ---- C: lane-per-cluster f64 eigen (32 lanes of wave 0) ----
    if (tid < CLB) {
        const int lc = tid;
        const int cl = (b << 8) + lo + lc;
        if (cl < C) {
            const int n = (int)hist[lc];
            double dn = (double)n;
            double nd = (double)max(n, 1);
            double cx = (double)mom[0][lc] / nd;
            double cy = (double)mom[1][lc] / nd;
            double cz = (double)mom[2][lc] / nd;

            double axx = (double)mom[3][lc] - dn * cx * cx;
            double axy = (double)mom[4][lc] - dn * cx * cy;
            double axz = (double)mom[5][lc] - dn * cx * cz;
            double ayy = (double)mom[6][lc] - dn * cy * cy;
            double ayz = (double)mom[7][lc] - dn * cy * cz;
            double azz = (double)mom[8][lc] - dn * cz * cz;

            double w0, w1, w2, v[3];
            eig3_sym(axx, axy, axz, ayy, ayz, azz, w0, w1, w2, v);

            double safe_w2 = (w2 > 0.0) ? w2 : 1.0;
            double isw = 1.0 / safe_w2;
            bool multi = (n >= 2);

            float fcx = (float)cx, fcy = (float)cy, fcz = (float)cz;
            float b3  = multi ? (float)(axx * isw) : 0.0f;
            float b4  = multi ? (float)(axy * isw) : 0.0f;
            float b5  = multi ? (float)(axz * isw) : 0.0f;
            float b7  = multi ? (float)(ayy * isw) : 0.0f;
            float b8  = multi ? (float)(ayz * isw) : 0.0f;
            float b11 = multi ? (float)(azz * isw) : 0.0f;

            float4* o = (float4*)(out + (size_t)cl * 16);
            o[0] = make_float4(fcx, fcy, fcz, b3);
            o[1] = make_float4(b4, b5, b4, b7);
            o[2] = make_float4(b8, b5, b8, b11);

            cenl[0][lc] = fcx; cenl[1][lc] = fcy; cenl[2][lc] = fcz;
            vvl[0][lc] = (float)v[0]; vvl[1][lc] = (float)v[1]; vvl[2][lc] = (float)v[2];
            dwl[lc] = (float)(1.0 - w1 / safe_w2);
        }
    }
    __syncthreads();

    // ---- D: sc from held registers -> final v0 ----
#pragma unroll
    for (int jj = 0; jj < 4; ++jj) {
        const int lc = (w << 2) | jj;
        const int cl = (b << 8) + lo + lc;
        if (cl >= C) continue;                  // wave-uniform
        const int n = nn[jj];
        const unsigned int nb = nbs[jj];
        float fcx = cenl[0][lc], fcy = cenl[1][lc], fcz = cenl[2][lc];
        float vx = vvl[0][lc], vy = vvl[1][lc], vz = vvl[2][lc];
        float sc = 0.0f;
        if (lane < n) {
            float x = qa[jj].x - fcx, y = qa[jj].y - fcy, z = qa[jj].z - fcz;
            float x0 = x * vx + y * vy + z * vz;
            float qx = x - x0 * vx, qy = y - x0 * vy, qz = z - x0 * vz;
            sc += x0 * sqrtf(qx * qx + qy * qy + qz * qz);
        }
        if (lane + 64 < n) {
            float x = qb[jj].x - fcx, y = qb[jj].y - fcy, z = qb[jj].z - fcz;
            float x0 = x * vx + y * vy + z * vz;
            float qx = x - x0 * vx, qy = y - x0 * vy, qz = z - x0 * vz;
            sc += x0 * sqrtf(qx * qx + qy * qy + qz * qz);
        }
        for (int j = lane + 128; j < n; j += 64) {
            unsigned int pp = nb + (unsigned)j;
            if (pp < IDXCAP) {
                float4 p = src[idx16[pp]];
                float x = p.x - fcx, y = p.y - fcy, z = p.z - fcz;
                float x0 = x * vx + y * vy + z * vz;
                float qx = x - x0 * vx, qy = y - x0 * vy, qz = z - x0 * vz;
                sc += x0 * sqrtf(qx * qx + qy * qy + qz * qz);
            }
        }
#pragma unroll
        for (int d = 32; d > 0; d >>= 1) sc += __shfl_xor(sc, d);

        if (lane == 0) {
            float sgn = (sc < 0.0f) ? -1.0f : 1.0f;
            float m = (n >= 2) ? sgn * dwl[lc] : 0.0f;
            ((float4*)(out + (size_t)cl * 16))[3] =
                make_float4(vx * m, vy * m, vz * m, (float)n);
        }
    }
}

// ============================ fallback path (round-2) ======================
#define FXP_SCALE 131072.0f
#define FXP_BIAS  4194304
#define FXP_INV   (1.0 / 131072.0)

__device__ __forceinline__ unsigned int fxp_enc(float v) {
    return (unsigned int)(__float2int_rn(v * FXP_SCALE) + FXP_BIAS);
}
__device__ __forceinline__ double fxp_dec(unsigned int s, int n) {
    return (double)((long long)s - (long long)n * FXP_BIAS) * FXP_INV;
}

__global__ void k1_accum(const float* __restrict__ data,
                         const int* __restrict__ cid,
                         unsigned long long* __restrict__ acc,
                         int n_vox) {
    int stride = gridDim.x * blockDim.x;
    for (int i = blockIdx.x * blockDim.x + threadIdx.x; i < n_vox; i += stride) {
        int c = cid[i];
        const float* row = data + (size_t)i * 6;
        float x = row[1], y = row[2], z = row[3];
        unsigned long long* a = acc + (size_t)c * 5;
        unsigned long long p0 = ((unsigned long long)fxp_enc(y)     << 32) | fxp_enc(x);
        unsigned long long p1 = ((unsigned long long)fxp_enc(x * x) << 32) | fxp_enc(z);
        unsigned long long p2 = ((unsigned long long)fxp_enc(x * z) << 32) | fxp_enc(x * y);
        unsigned long long p3 = ((unsigned long long)fxp_enc(y * z) << 32) | fxp_enc(y * y);
        unsigned long long p4 = (1ULL << 32)                               | fxp_enc(z * z);
        atomicAdd(&a[0], p0);
        atomicAdd(&a[1], p1);
        atomicAdd(&a[2], p2);
        atomicAdd(&a[3], p3);
        atomicAdd(&a[4], p4);
    }
}

__global__ void k2_cluster(const unsigned long long* __restrict__ acc,
                           float* __restrict__ wf,
                           float* __restrict__ out, int C) {
    int c = blockIdx.x * blockDim.x + threadIdx.x;
    if (c >= C) return;
    const unsigned long long* a = acc + (size_t)c * 5;
    unsigned long long s0 = a[0], s1 = a[1], s2 = a[2], s3 = a[3], s4 = a[4];
    int n = (int)(s4 >> 32);

    double sx  = fxp_dec((unsigned int)s0,         n);
    double sy  = fxp_dec((unsigned int)(s0 >> 32), n);
    double sz  = fxp_dec((unsigned int)s1,         n);
    double sxx = fxp_dec((unsigned int)(s1 >> 32), n);
    double sxy = fxp_dec((unsigned int)s2,         n);
    double sxz = fxp_dec((unsigned int)(s2 >> 32), n);
    double syy = fxp_dec((unsigned int)s3,         n);
    double syz = fxp_dec((unsigned int)(s3 >> 32), n);
    double szz = fxp_dec((unsigned int)s4,         n);

    double nd = (double)max(n, 1);
    double cx = sx / nd, cy = sy / nd, cz = sz / nd;
    double dn = (double)n;
    double axx = sxx - dn * cx * cx;
    double axy = sxy - dn * cx * cy;
    double axz = sxz - dn * cx * cz;
    double ayy = syy - dn * cy * cy;
    double ayz = syz - dn * cy * cz;
    double azz = szz - dn * cz * cz;

    double w0, w1, w2, v[3];
    eig3_sym(axx, axy, axz, ayy, ayz, azz, w0, w1, w2, v);

    double safe_w2 = (w2 > 0.0) ? w2 : 1.0;
    double dirwt   = 1.0 - w1 / safe_w2;
    double isw     = 1.0 / safe_w2;
    bool multi = (n >= 2);

    float* o = out + (size_t)c * 16;
    o[0] = (float)cx; o[1] = (float)cy; o[2] = (float)cz;
    if (multi) {
        o[3]  = (float)(axx * isw); o[4]  = (float)(axy * isw); o[5]  = (float)(axz * isw);
        o[6]  = (float)(axy * isw); o[7]  = (float)(ayy * isw); o[8]  = (float)(ayz * isw);
        o[9]  = (float)(axz * isw); o[10] = (float)(ayz * isw); o[11] = (float)(azz * isw);
    } else {
        o[3] = 0.f; o[4] = 0.f; o[5] = 0.f; o[6] = 0.f; o[7] = 0.f;
        o[8] = 0.f; o[9] = 0.f; o[10] = 0.f; o[11] = 0.f;
    }
    o[15] = (float)n;

    wf[(size_t)C * 1 + c] = (float)cx;
    wf[(size_t)C * 2 + c] = (float)cy;
    wf[(size_t)C * 3 + c] = (float)cz;
    wf[(size_t)C * 4 + c] = (float)v[0];
    wf[(size_t)C * 5 + c] = (float)v[1];
    wf[(size_t)C * 6 + c] = (float)v[2];
    wf[(size_t)C * 7 + c] = (float)dirwt;
}

__global__ void k3_sc(const float* __restrict__ data,
                      const int* __restrict__ cid,
                      float* __restrict__ wf,
                      int n_vox, int C) {
    const float* cenx = wf + (size_t)C * 1;
    const float* ceny = wf + (size_t)C * 2;
    const float* cenz = wf + (size_t)C * 3;
    const float* v0x  = wf + (size_t)C * 4;
    const float* v0y  = wf + (size_t)C * 5;
    const float* v0z  = wf + (size_t)C * 6;
    float* sc = wf;
    int stride = gridDim.x * blockDim.x;
    for (int i = blockIdx.x * blockDim.x + threadIdx.x; i < n_vox; i += stride) {
        int c = cid[i];
        const float* row = data + (size_t)i * 6;
        float x = row[1] - cenx[c];
        float y = row[2] - ceny[c];
        float z = row[3] - cenz[c];
        float vx = v0x[c], vy = v0y[c], vz = v0z[c];
        float x0 = x * vx + y * vy + z * vz;
        float px = x - x0 * vx;
        float py = y - x0 * vy;
        float pz = z - x0 * vz;
        atomicAdd(&sc[c], x0 * sqrtf(px * px + py * py + pz * pz));
    }
}

__global__ void k4_final(const unsigned long long* __restrict__ acc,
                         const float* __restrict__ wf,
                         float* __restrict__ out, int C) {
    int c = blockIdx.x * blockDim.x + threadIdx.x;
    if (c >= C) return;
    int n = (int)(acc[(size_t)c * 5 + 4] >> 32);
    float scv = wf[c];
    float vx  = wf[(size_t)C * 4 + c];
    float vy  = wf[(size_t)C * 5 + c];
    float vz  = wf[(size_t)C * 6 + c];
    float dir = wf[(size_t)C * 7 + c];
    float sgn = (scv < 0.0f) ? -1.0f : 1.0f;
    float m = (n >= 2) ? sgn * dir : 0.0f;
    float* o = out + (size_t)c * 16;
    o[12] = vx * m;
    o[13] = vy * m;
    o[14] = vz * m;
}

// ============================ launch =======================================
extern "C" void kernel_launch(void* const* d_in, const int* in_sizes, int n_in,
                              void* d_out, int out_size, void* d_ws, size_t ws_size,
                              hipStream_t stream) {
    const float* data = (const float*)d_in[0];
    const int*   cid  = (const int*)d_in[1];
    float* out = (float*)d_out;

    int n_vox = in_sizes[1];
    int C     = out_size / 16;

    int nbuckets = (C + 255) >> 8;
    long long expected = (C > 0) ? (long long)n_vox * 256 / C : 0;
    size_t bbuf_bytes = (size_t)nbuckets * CAP * 16;
    size_t need = 1024 + bbuf_bytes + (size_t)nbuckets * CAP;  // + lcb bytes

    if (C > 0 && nbuckets <= 256 && expected <= (CAP * 7) / 8 && ws_size >= need) {
        unsigned int* gcnt = (unsigned int*)d_ws;            // 256 * 4 = 1 KB
        float4* bbuf = (float4*)((char*)d_ws + 1024);
        unsigned char* lcb = (unsigned char*)((char*)d_ws + 1024 + bbuf_bytes);
        hipMemsetAsync(d_ws, 0, 1024, stream);
        p1_bucket<<<512, P1_BLOCK, 0, stream>>>(data, cid, gcnt, bbuf, lcb, n_vox);
        p2_features<<<nbuckets * SPLIT, 512, 0, stream>>>(gcnt, bbuf, lcb, out, C);
    } else {
        unsigned long long* acc = (unsigned long long*)d_ws;
        float* wf = (float*)((char*)d_ws + (size_t)C * 40);
        hipMemsetAsync(d_ws, 0, (size_t)C * 44, stream);
        const int vox_blocks = 4096;
        const int cl_blocks  = (C + 255) / 256;
        k1_accum<<<vox_blocks, 256, 0, stream>>>(data, cid, acc, n_vox);
        k2_cluster<<<cl_blocks, 256, 0, stream>>>(acc, wf, out, C);
        k3_sc<<<vox_blocks, 256, 0, stream>>>(data, cid, wf, n_vox, C);
        k4_final<<<cl_blocks, 256, 0, stream>>>(acc, wf, out, C);
    }
}

// Round 8
// 169.830 us; speedup vs baseline: 1.2656x; 1.2656x over previous
//
#include <hip/hip_runtime.h>
#include <math.h>

// ---------------------------------------------------------------------------
// ClustGeoNodeEncoder via two-level bucket decomposition.
//
// Measured walls: global atomics ~16-23 G ops/s (r2-r4); LDS-atomic moments at
// low parallelism serialize (r5); redundant per-wave f64 eigen is VALU-heavy
// (r6); splitting buckets across blocks destroys gather line-locality (r7).
// Design (r8): p1 buckets points (LDS-amortized alloc, ~250K global atomics);
// p2 is MONOLITHIC per bucket (line reuse) with BYTE-ARRAY sort passes (lcb)
// and LANE-PARALLEL eigen.
//
//   p1_bucket   : bucket = cid>>8 (196 buckets). Per 4096-voxel round: LDS
//                 ds_add_rtn local ranks + 256 returning global atomics
//                 allocate bucket space; scatter (x,y,z,cid)->bbuf, low cid
//                 byte -> lcb.
//   p2_features : 1 block (1024 thr) per bucket.
//                 A: hist+scan+counting-sort indices (reads lcb bytes only)
//                 B: 16 waves x 16 clusters: gather pts -> regs, shuffle-
//                    reduce 9 moments -> LDS
//                 C: lane-per-cluster f64 eigen (256 lanes) -> out[0..2],
//                    cen/v0/dirwt -> LDS
//                 D: re-gather (L2-hot) sc pass -> out[3]
// Fallback (small ws): round-2 packed u64 fixed-point pipeline.
// ---------------------------------------------------------------------------

#define CAP 24576          // per-bucket capacity (expected 20480 @ bench; +20%)

// ========================= shared: 3x3 symmetric eigen =====================
__device__ inline void eig3_sym(double a00, double a01, double a02,
                                double a11, double a12, double a22,
                                double& w0, double& w1, double& w2,
                                double v[3]) {
    double p1 = a01 * a01 + a02 * a02 + a12 * a12;
    double q  = (a00 + a11 + a22) / 3.0;
    double d0 = a00 - q, d1 = a11 - q, d2 = a22 - q;
    double p2 = d0 * d0 + d1 * d1 + d2 * d2 + 2.0 * p1;
    double p  = sqrt(p2 / 6.0);
    if (p < 1e-300) {
        w0 = w1 = w2 = q;
        v[0] = 0.0; v[1] = 0.0; v[2] = 1.0;
        return;
    }
    double ip = 1.0 / p;
    double b00 = d0 * ip, b11 = d1 * ip, b22 = d2 * ip;
    double b01 = a01 * ip, b02 = a02 * ip, b12 = a12 * ip;
    double detB = b00 * (b11 * b22 - b12 * b12)
                - b01 * (b01 * b22 - b12 * b02)
                + b02 * (b01 * b12 - b11 * b02);
    double r = detB * 0.5;
    r = fmin(1.0, fmax(-1.0, r));
    double phi = acos(r) / 3.0;
    w2 = q + 2.0 * p * cos(phi);
    w0 = q + 2.0 * p * cos(phi + 2.0943951023931953);  // +2*pi/3
    w1 = 3.0 * q - w2 - w0;

    double r0x = a00 - w2, r0y = a01,       r0z = a02;
    double r1x = a01,      r1y = a11 - w2,  r1z = a12;
    double r2x = a02,      r2y = a12,       r2z = a22 - w2;

    double c0x = r0y * r1z - r0z * r1y;
    double c0y = r0z * r1x - r0x * r1z;
    double c0z = r0x * r1y - r0y * r1x;
    double n0  = c0x * c0x + c0y * c0y + c0z * c0z;

    double c1x = r0y * r2z - r0z * r2y;
    double c1y = r0z * r2x - r0x * r2z;
    double c1z = r0x * r2y - r0y * r2x;
    double n1  = c1x * c1x + c1y * c1y + c1z * c1z;

    double c2x = r1y * r2z - r1z * r2y;
    double c2y = r1z * r2x - r1x * r2z;
    double c2z = r1x * r2y - r1y * r2x;
    double n2  = c2x * c2x + c2y * c2y + c2z * c2z;

    double vx, vy, vz, nn;
    if (n0 >= n1 && n0 >= n2) { vx = c0x; vy = c0y; vz = c0z; nn = n0; }
    else if (n1 >= n2)        { vx = c1x; vy = c1y; vz = c1z; nn = n1; }
    else                      { vx = c2x; vy = c2y; vz = c2z; nn = n2; }
    if (nn < 1e-300) {
        v[0] = 0.0; v[1] = 0.0; v[2] = 1.0;
        return;
    }
    double inv = rsqrt(nn);
    v[0] = vx * inv; v[1] = vy * inv; v[2] = vz * inv;
}

// ============================ primary path =================================
#define P1_BLOCK 1024
#define P1_ITEMS 4     // voxels per thread per round -> 4096 per block-round

__global__ void p1_bucket(const float* __restrict__ data,
                          const int* __restrict__ cid,
                          unsigned int* __restrict__ gcnt,     // [256]
                          float4* __restrict__ bbuf,           // [nb*CAP]
                          unsigned char* __restrict__ lcb,     // [nb*CAP]
                          int n_vox) {
    __shared__ unsigned int hist[256];
    __shared__ unsigned int base[256];
    const int tid = threadIdx.x;
    const int per_round = P1_BLOCK * P1_ITEMS;
    const int total_rounds = (n_vox + per_round - 1) / per_round;

    for (int r = blockIdx.x; r < total_rounds; r += gridDim.x) {
        const int start = r * per_round;
        if (tid < 256) hist[tid] = 0;
        __syncthreads();

        int   bk[P1_ITEMS];
        int   cd[P1_ITEMS];
        float px[P1_ITEMS], py[P1_ITEMS], pz[P1_ITEMS];
        unsigned int rk[P1_ITEMS];
#pragma unroll
        for (int k = 0; k < P1_ITEMS; ++k) {
            int i = start + tid + k * P1_BLOCK;   // coalesced lane pattern
            if (i < n_vox) {
                int c = cid[i];
                cd[k] = c;
                bk[k] = c >> 8;
                const float* row = data + (size_t)i * 6;
                px[k] = row[1]; py[k] = row[2]; pz[k] = row[3];
                rk[k] = atomicAdd(&hist[bk[k]], 1u);   // local rank
            } else {
                bk[k] = -1;
            }
        }
        __syncthreads();
        if (tid < 256) {
            unsigned int h = hist[tid];
            base[tid] = h ? atomicAdd(&gcnt[tid], h) : 0u;
        }
        __syncthreads();
#pragma unroll
        for (int k = 0; k < P1_ITEMS; ++k) {
            if (bk[k] >= 0) {
                unsigned int pos = base[bk[k]] + rk[k];
                if (pos < (unsigned int)CAP) {
                    bbuf[(size_t)bk[k] * CAP + pos] =
                        make_float4(px[k], py[k], pz[k], __int_as_float(cd[k]));
                    lcb[(size_t)bk[k] * CAP + pos] = (unsigned char)(cd[k] & 255);
                }
            }
        }
        __syncthreads();
    }
}

__global__ __launch_bounds__(1024) void p2_features(
        const unsigned int* __restrict__ gcnt,
        const float4* __restrict__ bbuf,
        const unsigned char* __restrict__ lcb,
        float* __restrict__ out, int C) {
    __shared__ unsigned int hist[256];
    __shared__ unsigned int basex[256];
    __shared__ unsigned int hist2[256];
    __shared__ unsigned short idx16[CAP];       // 48 KB
    __shared__ float mom[9][256];
    __shared__ float cenl[3][256], vvl[3][256], dwl[256];

    const int b   = blockIdx.x;
    const int tid = threadIdx.x;
    const int bcnt = min((int)gcnt[b], CAP);
    const float4* src = bbuf + (size_t)b * CAP;
    const unsigned char* lc8 = lcb + (size_t)b * CAP;

    if (tid < 256) { hist[tid] = 0; hist2[tid] = 0; }
    __syncthreads();

    // ---- A1: histogram from byte array (uchar4 loads) ----
    const int n4 = (bcnt + 3) >> 2;
    for (int g = tid; g < n4; g += 1024) {
        uchar4 c4 = *reinterpret_cast<const uchar4*>(lc8 + 4 * g);
        int i = 4 * g;
        if (i + 0 < bcnt) atomicAdd(&hist[c4.x], 1u);
        if (i + 1 < bcnt) atomicAdd(&hist[c4.y], 1u);
        if (i + 2 < bcnt) atomicAdd(&hist[c4.z], 1u);
        if (i + 3 < bcnt) atomicAdd(&hist[c4.w], 1u);
    }
    __syncthreads();

    // ---- exclusive scan over 256 (Hillis-Steele) ----
    if (tid < 256) basex[tid] = hist[tid];
    __syncthreads();
    for (int off = 1; off < 256; off <<= 1) {
        unsigned int v = 0;
        if (tid < 256 && tid >= off) v = basex[tid - off];
        __syncthreads();
        if (tid < 256) basex[tid] += v;
        __syncthreads();
    }
    if (tid < 256) basex[tid] -= hist[tid];
    __syncthreads();

    // ---- A2: counting-sort indices (byte reads again) ----
    for (int g = tid; g < n4; g += 1024) {
        uchar4 c4 = *reinterpret_cast<const uchar4*>(lc8 + 4 * g);
        int i = 4 * g;
        if (i + 0 < bcnt) { unsigned int rk = atomicAdd(&hist2[c4.x], 1u); idx16[basex[c4.x] + rk] = (unsigned short)(i + 0); }
        if (i + 1 < bcnt) { unsigned int rk = atomicAdd(&hist2[c4.y], 1u); idx16[basex[c4.y] + rk] = (unsigned short)(i + 1); }
        if (i + 2 < bcnt) { unsigned int rk = atomicAdd(&hist2[c4.z], 1u); idx16[basex[c4.z] + rk] = (unsigned short)(i + 2); }
        if (i + 3 < bcnt) { unsigned int rk = atomicAdd(&hist2[c4.w], 1u); idx16[basex[c4.w] + rk] = (unsigned short)(i + 3); }
    }
    __syncthreads();

    const int w    = tid >> 6;     // 0..15
    const int lane = tid & 63;

    // ---- B: wave-per-cluster moments (gather, full-line L1/L2 reuse) ----
#pragma unroll 1
    for (int jj = 0; jj < 16; ++jj) {
        const int t = (w << 4) | jj;
        const int n = (int)hist[t];
        const unsigned int nb = basex[t];

        float4 z = make_float4(0.f, 0.f, 0.f, 0.f);
        float4 q0 = z, q1 = z, q2 = z;
        if (lane < n)       q0 = src[idx16[nb + lane]];
        if (lane + 64 < n)  q1 = src[idx16[nb + lane + 64]];
        if (lane + 128 < n) q2 = src[idx16[nb + lane + 128]];

        float s0 = q0.x + q1.x + q2.x;
        float s1 = q0.y + q1.y + q2.y;
        float s2 = q0.z + q1.z + q2.z;
        float s3 = q0.x * q0.x + q1.x * q1.x + q2.x * q2.x;
        float s4 = q0.x * q0.y + q1.x * q1.y + q2.x * q2.y;
        float s5 = q0.x * q0.z + q1.x * q1.z + q2.x * q2.z;
        float s6 = q0.y * q0.y + q1.y * q1.y + q2.y * q2.y;
        float s7 = q0.y * q0.z + q1.y * q1.z + q2.y * q2.z;
        float s8 = q0.z * q0.z + q1.z * q1.z + q2.z * q2.z;
        for (int j = lane + 192; j < n; j += 64) {      // rare n>192 tail
            float4 p = src[idx16[nb + j]];
            s0 += p.x;       s1 += p.y;       s2 += p.z;
            s3 += p.x * p.x; s4 += p.x * p.y; s5 += p.x * p.z;
            s6 += p.y * p.y; s7 += p.y * p.z; s8 += p.z * p.z;
        }
#pragma unroll
        for (int d = 32; d > 0; d >>= 1) {
            s0 += __shfl_xor(s0, d); s1 += __shfl_xor(s1, d); s2 += __shfl_xor(s2, d);
            s3 += __shfl_xor(s3, d); s4 += __shfl_xor(s4, d); s5 += __shfl_xor(s5, d);
            s6 += __shfl_xor(s6, d); s7 += __shfl_xor(s7, d); s8 += __shfl_xor(s8, d);
        }
        if (lane == 0) {
            mom[0][t] = s0; mom[1][t] = s1; mom[2][t] = s2;
            mom[3][t] = s3; mom[4][t] = s4; mom[5][t] = s5;
            mom[6][t] = s6; mom[7][t] = s7; mom[8][t] = s8;
        }
    }
    __syncthreads();

    // ---- C: lane-per-cluster f64 eigen (256 lanes busy) ----
    if (tid < 256) {
        const int t  = tid;
        const int cl = (b << 8) + t;
        if (cl < C) {
            const int n = (int)hist[t];
            double dn = (double)n;
            double nd = (double)max(n, 1);
            double cx = (double)mom[0][t] / nd;
            double cy = (double)mom[1][t] / nd;
            double cz = (double)mom[2][t] / nd;

            double axx = (double)mom[3][t] - dn * cx * cx;
            double axy = (double)mom[4][t] - dn * cx * cy;
            double axz = (double)mom[5][t] - dn * cx * cz;
            double ayy = (double)mom[6][t] - dn * cy * cy;
            double ayz = (double)mom[7][t] - dn * cy * cz;
            double azz = (double)mom[8][t] - dn * cz * cz;

            double w0, w1, w2, v[3];
            eig3_sym(axx, axy, axz, ayy, ayz, azz, w0, w1, w2, v);

            double safe_w2 = (w2 > 0.0) ? w2 : 1.0;
            double isw = 1.0 / safe_w2;
            bool multi = (n >= 2);

            float fcx = (float)cx, fcy = (float)cy, fcz = (float)cz;
            float b3  = multi ? (float)(axx * isw) : 0.0f;
            float b4  = multi ? (float)(axy * isw) : 0.0f;
            float b5  = multi ? (float)(axz * isw) : 0.0f;
            float b7  = multi ? (float)(ayy * isw) : 0.0f;
            float b8  = multi ? (float)(ayz * isw) : 0.0f;
            float b11 = multi ? (float)(azz * isw) : 0.0f;

            float4* o = (float4*)(out + (size_t)cl * 16);
            o[0] = make_float4(fcx, fcy, fcz, b3);
            o[1] = make_float4(b4, b5, b4, b7);
            o[2] = make_float4(b8, b5, b8, b11);

            cenl[0][t] = fcx; cenl[1][t] = fcy; cenl[2][t] = fcz;
            vvl[0][t] = (float)v[0]; vvl[1][t] = (float)v[1]; vvl[2][t] = (float)v[2];
            dwl[t] = (float)(1.0 - w1 / safe_w2);
        }
    }
    __syncthreads();

    // ---- D: sc pass (re-gather; bucket window is L1/L2-hot) ----
#pragma unroll 1
    for (int jj = 0; jj < 16; ++jj) {
        const int t  = (w << 4) | jj;
        const int cl = (b << 8) + t;
        if (cl >= C) continue;                  // wave-uniform
        const int n = (int)hist[t];
        const unsigned int nb = basex[t];
        const float fcx = cenl[0][t], fcy = cenl[1][t], fcz = cenl[2][t];
        const float vx = vvl[0][t], vy = vvl[1][t], vz = vvl[2][t];
        float sc = 0.0f;
        for (int j = lane; j < n; j += 64) {
            float4 p = src[idx16[nb + j]];
            float x = p.x - fcx, y = p.y - fcy, z = p.z - fcz;
            float x0 = x * vx + y * vy + z * vz;
            float qx = x - x0 * vx, qy = y - x0 * vy, qz = z - x0 * vz;
            sc += x0 * sqrtf(qx * qx + qy * qy + qz * qz);
        }
#pragma unroll
        for (int d = 32; d > 0; d >>= 1) sc += __shfl_xor(sc, d);

        if (lane == 0) {
            float sgn = (sc < 0.0f) ? -1.0f : 1.0f;
            float m = (n >= 2) ? sgn * dwl[t] : 0.0f;
            ((float4*)(out + (size_t)cl * 16))[3] =
                make_float4(vx * m, vy * m, vz * m, (float)n);
        }
    }
}

// ============================ fallback path (round-2) ======================
#define FXP_SCALE 131072.0f
#define FXP_BIAS  4194304
#define FXP_INV   (1.0 / 131072.0)

__device__ __forceinline__ unsigned int fxp_enc(float v) {
    return (unsigned int)(__float2int_rn(v * FXP_SCALE) + FXP_BIAS);
}
__device__ __forceinline__ double fxp_dec(unsigned int s, int n) {
    return (double)((long long)s - (long long)n * FXP_BIAS) * FXP_INV;
}

__global__ void k1_accum(const float* __restrict__ data,
                         const int* __restrict__ cid,
                         unsigned long long* __restrict__ acc,
                         int n_vox) {
    int stride = gridDim.x * blockDim.x;
    for (int i = blockIdx.x * blockDim.x + threadIdx.x; i < n_vox; i += stride) {
        int c = cid[i];
        const float* row = data + (size_t)i * 6;
        float x = row[1], y = row[2], z = row[3];
        unsigned long long* a = acc + (size_t)c * 5;
        unsigned long long p0 = ((unsigned long long)fxp_enc(y)     << 32) | fxp_enc(x);
        unsigned long long p1 = ((unsigned long long)fxp_enc(x * x) << 32) | fxp_enc(z);
        unsigned long long p2 = ((unsigned long long)fxp_enc(x * z) << 32) | fxp_enc(x * y);
        unsigned long long p3 = ((unsigned long long)fxp_enc(y * z) << 32) | fxp_enc(y * y);
        unsigned long long p4 = (1ULL << 32)                               | fxp_enc(z * z);
        atomicAdd(&a[0], p0);
        atomicAdd(&a[1], p1);
        atomicAdd(&a[2], p2);
        atomicAdd(&a[3], p3);
        atomicAdd(&a[4], p4);
    }
}

__global__ void k2_cluster(const unsigned long long* __restrict__ acc,
                           float* __restrict__ wf,
                           float* __restrict__ out, int C) {
    int c = blockIdx.x * blockDim.x + threadIdx.x;
    if (c >= C) return;
    const unsigned long long* a = acc + (size_t)c * 5;
    unsigned long long s0 = a[0], s1 = a[1], s2 = a[2], s3 = a[3], s4 = a[4];
    int n = (int)(s4 >> 32);

    double sx  = fxp_dec((unsigned int)s0,         n);
    double sy  = fxp_dec((unsigned int)(s0 >> 32), n);
    double sz  = fxp_dec((unsigned int)s1,         n);
    double sxx = fxp_dec((unsigned int)(s1 >> 32), n);
    double sxy = fxp_dec((unsigned int)s2,         n);
    double sxz = fxp_dec((unsigned int)(s2 >> 32), n);
    double syy = fxp_dec((unsigned int)s3,         n);
    double syz = fxp_dec((unsigned int)(s3 >> 32), n);
    double szz = fxp_dec((unsigned int)s4,         n);

    double nd = (double)max(n, 1);
    double cx = sx / nd, cy = sy / nd, cz = sz / nd;
    double dn = (double)n;
    double axx = sxx - dn * cx * cx;
    double axy = sxy - dn * cx * cy;
    double axz = sxz - dn * cx * cz;
    double ayy = syy - dn * cy * cy;
    double ayz = syz - dn * cy * cz;
    double azz = szz - dn * cz * cz;

    double w0, w1, w2, v[3];
    eig3_sym(axx, axy, axz, ayy, ayz, azz, w0, w1, w2, v);

    double safe_w2 = (w2 > 0.0) ? w2 : 1.0;
    double dirwt   = 1.0 - w1 / safe_w2;
    double isw     = 1.0 / safe_w2;
    bool multi = (n >= 2);

    float* o = out + (size_t)c * 16;
    o[0] = (float)cx; o[1] = (float)cy; o[2] = (float)cz;
    if (multi) {
        o[3]  = (float)(axx * isw); o[4]  = (float)(axy * isw); o[5]  = (float)(axz * isw);
        o[6]  = (float)(axy * isw); o[7]  = (float)(ayy * isw); o[8]  = (float)(ayz * isw);
        o[9]  = (float)(axz * isw); o[10] = (float)(ayz * isw); o[11] = (float)(azz * isw);
    } else {
        o[3] = 0.f; o[4] = 0.f; o[5] = 0.f; o[6] = 0.f; o[7] = 0.f;
        o[8] = 0.f; o[9] = 0.f; o[10] = 0.f; o[11] = 0.f;
    }
    o[15] = (float)n;

    wf[(size_t)C * 1 + c] = (float)cx;
    wf[(size_t)C * 2 + c] = (float)cy;
    wf[(size_t)C * 3 + c] = (float)cz;
    wf[(size_t)C * 4 + c] = (float)v[0];
    wf[(size_t)C * 5 + c] = (float)v[1];
    wf[(size_t)C * 6 + c] = (float)v[2];
    wf[(size_t)C * 7 + c] = (float)dirwt;
}

__global__ void k3_sc(const float* __restrict__ data,
                      const int* __restrict__ cid,
                      float* __restrict__ wf,
                      int n_vox, int C) {
    const float* cenx = wf + (size_t)C * 1;
    const float* ceny = wf + (size_t)C * 2;
    const float* cenz = wf + (size_t)C * 3;
    const float* v0x  = wf + (size_t)C * 4;
    const float* v0y  = wf + (size_t)C * 5;
    const float* v0z  = wf + (size_t)C * 6;
    float* sc = wf;
    int stride = gridDim.x * blockDim.x;
    for (int i = blockIdx.x * blockDim.x + threadIdx.x; i < n_vox; i += stride) {
        int c = cid[i];
        const float* row = data + (size_t)i * 6;
        float x = row[1] - cenx[c];
        float y = row[2] - ceny[c];
        float z = row[3] - cenz[c];
        float vx = v0x[c], vy = v0y[c], vz = v0z[c];
        float x0 = x * vx + y * vy + z * vz;
        float px = x - x0 * vx;
        float py = y - x0 * vy;
        float pz = z - x0 * vz;
        atomicAdd(&sc[c], x0 * sqrtf(px * px + py * py + pz * pz));
    }
}

__global__ void k4_final(const unsigned long long* __restrict__ acc,
                         const float* __restrict__ wf,
                         float* __restrict__ out, int C) {
    int c = blockIdx.x * blockDim.x + threadIdx.x;
    if (c >= C) return;
    int n = (int)(acc[(size_t)c * 5 + 4] >> 32);
    float scv = wf[c];
    float vx  = wf[(size_t)C * 4 + c];
    float vy  = wf[(size_t)C * 5 + c];
    float vz  = wf[(size_t)C * 6 + c];
    float dir = wf[(size_t)C * 7 + c];
    float sgn = (scv < 0.0f) ? -1.0f : 1.0f;
    float m = (n >= 2) ? sgn * dir : 0.0f;
    float* o = out + (size_t)c * 16;
    o[12] = vx * m;
    o[13] = vy * m;
    o[14] = vz * m;
}

// ============================ launch =======================================
extern "C" void kernel_launch(void* const* d_in, const int* in_sizes, int n_in,
                              void* d_out, int out_size, void* d_ws, size_t ws_size,
                              hipStream_t stream) {
    const float* data = (const float*)d_in[0];
    const int*   cid  = (const int*)d_in[1];
    float* out = (float*)d_out;

    int n_vox = in_sizes[1];
    int C     = out_size / 16;

    int nbuckets = (C + 255) >> 8;
    long long expected = (C > 0) ? (long long)n_vox * 256 / C : 0;
    size_t bbuf_bytes = (size_t)nbuckets * CAP * 16;
    size_t need = 1024 + bbuf_bytes + (size_t)nbuckets * CAP;  // + lcb bytes

    if (C > 0 && nbuckets <= 256 && expected <= (CAP * 7) / 8 && ws_size >= need) {
        unsigned int* gcnt = (unsigned int*)d_ws;            // 256 * 4 = 1 KB
        float4* bbuf = (float4*)((char*)d_ws + 1024);
        unsigned char* lcb = (unsigned char*)((char*)d_ws + 1024 + bbuf_bytes);
        hipMemsetAsync(d_ws, 0, 1024, stream);
        p1_bucket<<<512, P1_BLOCK, 0, stream>>>(data, cid, gcnt, bbuf, lcb, n_vox);
        p2_features<<<nbuckets, 1024, 0, stream>>>(gcnt, bbuf, lcb, out, C);
    } else {
        unsigned long long* acc = (unsigned long long*)d_ws;
        float* wf = (float*)((char*)d_ws + (size_t)C * 40);
        hipMemsetAsync(d_ws, 0, (size_t)C * 44, stream);
        const int vox_blocks = 4096;
        const int cl_blocks  = (C + 255) / 256;
        k1_accum<<<vox_blocks, 256, 0, stream>>>(data, cid, acc, n_vox);
        k2_cluster<<<cl_blocks, 256, 0, stream>>>(acc, wf, out, C);
        k3_sc<<<vox_blocks, 256, 0, stream>>>(data, cid, wf, n_vox, C);
        k4_final<<<cl_blocks, 256, 0, stream>>>(acc, wf, out, C);
    }
}